// Round 12
// baseline (205.583 us; speedup 1.0000x reference)
//
#include <hip/hip_runtime.h>

typedef __attribute__((ext_vector_type(8))) short bf16x8;
typedef __attribute__((ext_vector_type(4))) float f32x4;

#define MFMA16(A,B,C) __builtin_amdgcn_mfma_f32_16x16x32_bf16(A,B,C,0,0,0)

__device__ __forceinline__ unsigned short f2bf(float f){
  unsigned int u = __float_as_uint(f);
  u += 0x7FFFu + ((u >> 16) & 1u);        // round-to-nearest-even
  return (unsigned short)(u >> 16);
}
__device__ __forceinline__ float bf2f(unsigned short s){
  return __uint_as_float(((unsigned int)s) << 16);
}
// byte offset into a [rows][64] bf16 LDS tile (128B rows), XOR-swizzled (G4)
__device__ __forceinline__ int swz(int row, int kbyte){
  return (row * 128 + kbyte) ^ ((row & 7) << 4);
}

// ---------------- prep: transpose weights to n-major bf16 ------------------
__global__ __launch_bounds__(256) void k_prep(
    const float* __restrict__ w_qkv, const float* __restrict__ w_out,
    unsigned short* __restrict__ wqT, unsigned short* __restrict__ woT)
{
  int idx = blockIdx.x * 256 + threadIdx.x;
  if (idx < 1536 * 512) {
    int n = idx >> 9, kq = idx & 511;
    wqT[idx] = f2bf(w_qkv[(size_t)kq * 1536 + n]);
  } else {
    int j = idx - 1536 * 512;                  // < 262144
    int n = j >> 9, kq = j & 511;
    woT[j] = f2bf(w_out[(size_t)kq * 512 + n]);
  }
}

// ------ bias precompute: biasT[h][v][w] = rpe[h][hop[v][w]], w contiguous --
__global__ __launch_bounds__(256) void k_bias(
    const int* __restrict__ hop, const float* __restrict__ rpe_bias,
    unsigned short* __restrict__ biasT)
{
  __shared__ float rl[72];
  const int tid = threadIdx.x;
  if (tid < 72) rl[tid] = rpe_bias[tid];
  __syncthreads();
  const int idx = blockIdx.x * 256 + tid;      // (v,w) flat, coalesced
  const int hv = hop[idx];
#pragma unroll
  for (int h = 0; h < 8; ++h)
    biasT[((size_t)h << 20) + idx] = f2bf(rl[h * 9 + hv]);
}

// ---------------- QKV GEMM: qkv = x @ w_qkv (MFMA, bf16 in / f32 acc) ------
__global__ __launch_bounds__(256) void k_qkv(
    const float* __restrict__ x, const unsigned short* __restrict__ wqT,
    unsigned short* __restrict__ q, unsigned short* __restrict__ k_,
    unsigned short* __restrict__ valT)
{
  __shared__ char lds[32768];
  char* At = lds; char* Bt = lds + 16384;
  const int tid = threadIdx.x;
  const int wid = tid >> 6, lane = tid & 63, g = lane >> 4, r = lane & 15;
  const int wm = wid >> 1, wn = wid & 1;
  const int m0 = blockIdx.x * 128, n0 = blockIdx.y * 128;

  f32x4 acc[4][4];
#pragma unroll
  for (int a = 0; a < 4; ++a)
#pragma unroll
    for (int b = 0; b < 4; ++b) acc[a][b] = (f32x4){0.f, 0.f, 0.f, 0.f};

  for (int kt = 0; kt < 8; ++kt) {
    const int k0 = kt * 64;
    __syncthreads();
#pragma unroll
    for (int it = 0; it < 8; ++it) {
      int c = tid + it * 256;            // 128 rows x 16 chunks(4 f32)
      int row = c >> 4, c4 = c & 15;
      float4 xv = *reinterpret_cast<const float4*>(x + (size_t)(m0 + row) * 512 + k0 + c4 * 4);
      uint2 hv;
      hv.x = (unsigned)f2bf(xv.x) | ((unsigned)f2bf(xv.y) << 16);
      hv.y = (unsigned)f2bf(xv.z) | ((unsigned)f2bf(xv.w) << 16);
      *reinterpret_cast<uint2*>(At + swz(row, c4 * 8)) = hv;
    }
#pragma unroll
    for (int it = 0; it < 4; ++it) {
      int c = tid + it * 256;            // 128 rows x 8 chunks(16B)
      int row = c >> 3, c8 = c & 7;
      *reinterpret_cast<uint4*>(Bt + swz(row, c8 * 16)) =
          *reinterpret_cast<const uint4*>(wqT + (size_t)(n0 + row) * 512 + k0 + c8 * 8);
    }
    __syncthreads();
#pragma unroll
    for (int kk = 0; kk < 2; ++kk) {
      bf16x8 af[4], bf[4];
      const int kb = (kk * 32 + 8 * g) * 2;
#pragma unroll
      for (int mi = 0; mi < 4; ++mi)
        af[mi] = *reinterpret_cast<const bf16x8*>(At + swz(wm * 64 + mi * 16 + r, kb));
#pragma unroll
      for (int ni = 0; ni < 4; ++ni)
        bf[ni] = *reinterpret_cast<const bf16x8*>(Bt + swz(wn * 64 + ni * 16 + r, kb));
#pragma unroll
      for (int mi = 0; mi < 4; ++mi)
#pragma unroll
        for (int ni = 0; ni < 4; ++ni)
          acc[mi][ni] = MFMA16(af[mi], bf[ni], acc[mi][ni]);
    }
  }
  const int s = n0 >> 9;  // 0=q 1=k 2=val
#pragma unroll
  for (int mi = 0; mi < 4; ++mi)
#pragma unroll
    for (int ni = 0; ni < 4; ++ni)
#pragma unroll
      for (int i = 0; i < 4; ++i) {
        int m = m0 + wm * 64 + mi * 16 + 4 * g + i;   // D row = 4g+i (m89)
        int n = n0 + wn * 64 + ni * 16 + r;           // D col = lane&15
        int b = m >> 10, v = m & 1023;
        int cc = n & 511, h = cc >> 6, d = cc & 63;
        int bh = b * 8 + h;
        unsigned short bfv = f2bf(acc[mi][ni][i]);
        if (s == 2)      valT[((size_t)bh * 64 + d) * 1024 + v] = bfv;
        else if (s == 0) q [((size_t)bh * 1024 + v) * 64 + d] = bfv;
        else             k_[((size_t)bh * 1024 + v) * 64 + d] = bfv;
      }
}

// ---------------- attention: regs-scores + shfl softmax + PV ---------------
// One block = (b,h, 16 q-rows). Wave w owns score cols [256w, 256w+256).
// LDS P buffer triple-duty: bias tile during QK, then bf16 P (attn src + PV A).
// XCD swizzle: the 64 blocks sharing one (b,h) K/V slab land on ONE XCD's L2.
#define PSTR 1032
__global__ __launch_bounds__(256, 3) void k_attn(
    const unsigned short* __restrict__ q, const unsigned short* __restrict__ k_,
    const unsigned short* __restrict__ valT,
    const unsigned short* __restrict__ biasT,
    float* __restrict__ attn, unsigned short* __restrict__ oh)
{
  __shared__ unsigned short P[16 * PSTR];   // bf16, 33 KB
  __shared__ float red[2][4][16];
  const int tid = threadIdx.x;
  const int wid = tid >> 6, lane = tid & 63, g = lane >> 4, r = lane & 15;
  // T1 XCD-aware remap (4096 % 8 == 0 -> bijective): XCD j owns bh in [8j,8j+8)
  const int blk = ((blockIdx.x & 7) << 9) | (blockIdx.x >> 3);
  const int vt = blk & 63, bh = blk >> 6, h = bh & 7;
  const int v0 = vt * 16;

  // stage bias tile [16 rows][1024 w] bf16 into P (uint4 = 8 elems, coalesced)
  const unsigned short* bb = biasT + ((size_t)h << 20) + (size_t)v0 * 1024;
#pragma unroll
  for (int it = 0; it < 8; ++it) {
    int e = tid + it * 256;                  // 0..2047: row=e>>7, chunk=e&127
    int row = e >> 7, c8 = e & 127;
    *reinterpret_cast<uint4*>(&P[row * PSTR + c8 * 8]) =
        *reinterpret_cast<const uint4*>(bb + (size_t)row * 1024 + c8 * 8);
  }

  // Q fragments in registers (A-operand: row=r, k-slice 8g)
  const unsigned short* qp = q + ((size_t)bh * 1024 + v0) * 64;
  bf16x8 qf[2];
#pragma unroll
  for (int kk = 0; kk < 2; ++kk)
    qf[kk] = *reinterpret_cast<const bf16x8*>(qp + r * 64 + kk * 32 + 8 * g);
  __syncthreads();

  // QK: scores in registers; bias from LDS
  const unsigned short* kb = k_ + (size_t)bh * 65536;
  f32x4 s[16];
#pragma unroll
  for (int ct = 0; ct < 16; ++ct) {
    const int wcol = wid * 256 + ct * 16 + r;
    f32x4 acc = (f32x4){0.f, 0.f, 0.f, 0.f};
#pragma unroll
    for (int kk = 0; kk < 2; ++kk) {
      bf16x8 kf = *reinterpret_cast<const bf16x8*>(kb + (size_t)wcol * 64 + kk * 32 + 8 * g);
      acc = MFMA16(qf[kk], kf, acc);
    }
#pragma unroll
    for (int i = 0; i < 4; ++i)
      s[ct][i] = (acc[i] + bf2f(P[(4 * g + i) * PSTR + wcol])) * 0.125f;
  }

  // per-row max: local over ct, then shfl over the 16-lane r-group
  float mx[4] = {-1e30f, -1e30f, -1e30f, -1e30f};
#pragma unroll
  for (int ct = 0; ct < 16; ++ct)
#pragma unroll
    for (int i = 0; i < 4; ++i) mx[i] = fmaxf(mx[i], s[ct][i]);
#pragma unroll
  for (int o = 1; o <= 8; o <<= 1)
#pragma unroll
    for (int i = 0; i < 4; ++i) mx[i] = fmaxf(mx[i], __shfl_xor(mx[i], o, 64));
  if (r == 0)
#pragma unroll
    for (int i = 0; i < 4; ++i) red[0][wid][4 * g + i] = mx[i];
  __syncthreads();
#pragma unroll
  for (int i = 0; i < 4; ++i) {
    float M = red[0][0][4 * g + i];
#pragma unroll
    for (int w = 1; w < 4; ++w) M = fmaxf(M, red[0][w][4 * g + i]);
    mx[i] = M;
  }

  // exp + per-row sum
  float sm[4] = {0.f, 0.f, 0.f, 0.f};
#pragma unroll
  for (int ct = 0; ct < 16; ++ct)
#pragma unroll
    for (int i = 0; i < 4; ++i) {
      float e = __expf(s[ct][i] - mx[i]);
      s[ct][i] = e;
      sm[i] += e;
    }
#pragma unroll
  for (int o = 1; o <= 8; o <<= 1)
#pragma unroll
    for (int i = 0; i < 4; ++i) sm[i] += __shfl_xor(sm[i], o, 64);
  if (r == 0)
#pragma unroll
    for (int i = 0; i < 4; ++i) red[1][wid][4 * g + i] = sm[i];
  __syncthreads();                 // all QK bias reads done before P overwrite
  float inv[4];
#pragma unroll
  for (int i = 0; i < 4; ++i) {
    float T = red[1][0][4 * g + i] + red[1][1][4 * g + i] +
              red[1][2][4 * g + i] + red[1][3][4 * g + i];
    inv[i] = 1.0f / T;
  }

  // normalize into bf16 P only (no scattered global writes)
#pragma unroll
  for (int ct = 0; ct < 16; ++ct) {
    const int col = wid * 256 + ct * 16 + r;
#pragma unroll
    for (int i = 0; i < 4; ++i)
      P[(4 * g + i) * PSTR + col] = f2bf(s[ct][i] * inv[i]);
  }
  __syncthreads();

  // coalesced attn write from P: lane -> f32x4 (16B), 1KB contiguous per wave.
  float* ab = attn + ((size_t)bh * 1024 + v0) * 1024;
#pragma unroll
  for (int it = 0; it < 16; ++it) {
    int e = tid + it * 256;                 // 0..4095: row=e>>8, quad=e&255
    int row = e >> 8, q4 = e & 255;
    uint2 pv = *reinterpret_cast<const uint2*>(&P[row * PSTR + q4 * 4]);
    f32x4 o;
    o[0] = bf2f((unsigned short)(pv.x      ));
    o[1] = bf2f((unsigned short)(pv.x >> 16));
    o[2] = bf2f((unsigned short)(pv.y      ));
    o[3] = bf2f((unsigned short)(pv.y >> 16));
    __builtin_nontemporal_store(o, reinterpret_cast<f32x4*>(ab + (size_t)row * 1024 + q4 * 4));
  }

  // PV: out(16x64) = P(16x1024) @ val(1024x64); wave owns 16 out cols.
  const unsigned short* vT = valT + ((size_t)bh * 64 + wid * 16) * 1024;
  f32x4 a0 = (f32x4){0.f,0.f,0.f,0.f}, a1 = a0;
  for (int kc = 0; kc < 32; kc += 2) {
    const int base = r * PSTR, vbase = kc * 32 + 8 * g;
    bf16x8 p0 = *reinterpret_cast<const bf16x8*>(&P[base + vbase]);
    bf16x8 p1 = *reinterpret_cast<const bf16x8*>(&P[base + vbase + 32]);
    bf16x8 v0_ = *reinterpret_cast<const bf16x8*>(vT + (size_t)r * 1024 + vbase);
    bf16x8 v1_ = *reinterpret_cast<const bf16x8*>(vT + (size_t)r * 1024 + vbase + 32);
    a0 = MFMA16(p0, v0_, a0);
    a1 = MFMA16(p1, v1_, a1);
  }
  f32x4 acc = a0 + a1;
  const int b = bh >> 3;
#pragma unroll
  for (int i = 0; i < 4; ++i) {
    size_t oi = ((size_t)(b * 1024 + v0 + 4 * g + i)) * 512 + h * 64 + wid * 16 + r;
    oh[oi] = f2bf(acc[i]);
  }
}

// ---------------- output GEMM: out = oh @ w_out + b_out (f32 out) ----------
__global__ __launch_bounds__(256) void k_out(
    const unsigned short* __restrict__ oh, const unsigned short* __restrict__ woT,
    const float* __restrict__ b_out, float* __restrict__ out)
{
  __shared__ char lds[32768];
  char* At = lds; char* Bt = lds + 16384;
  const int tid = threadIdx.x;
  const int wid = tid >> 6, lane = tid & 63, g = lane >> 4, r = lane & 15;
  const int wm = wid >> 1, wn = wid & 1;
  const int m0 = blockIdx.x * 128, n0 = blockIdx.y * 128;

  f32x4 acc[4][4];
#pragma unroll
  for (int a = 0; a < 4; ++a)
#pragma unroll
    for (int b = 0; b < 4; ++b) acc[a][b] = (f32x4){0.f, 0.f, 0.f, 0.f};

  for (int kt = 0; kt < 8; ++kt) {
    const int k0 = kt * 64;
    __syncthreads();
#pragma unroll
    for (int it = 0; it < 4; ++it) {
      int c = tid + it * 256;
      int row = c >> 3, c8 = c & 7;
      *reinterpret_cast<uint4*>(At + swz(row, c8 * 16)) =
          *reinterpret_cast<const uint4*>(oh + (size_t)(m0 + row) * 512 + k0 + c8 * 8);
      *reinterpret_cast<uint4*>(Bt + swz(row, c8 * 16)) =
          *reinterpret_cast<const uint4*>(woT + (size_t)(n0 + row) * 512 + k0 + c8 * 8);
    }
    __syncthreads();
#pragma unroll
    for (int kk = 0; kk < 2; ++kk) {
      bf16x8 a4[4], b4[4];
      const int kb = (kk * 32 + 8 * g) * 2;
#pragma unroll
      for (int mi = 0; mi < 4; ++mi)
        a4[mi] = *reinterpret_cast<const bf16x8*>(At + swz(wm * 64 + mi * 16 + r, kb));
#pragma unroll
      for (int ni = 0; ni < 4; ++ni)
        b4[ni] = *reinterpret_cast<const bf16x8*>(Bt + swz(wn * 64 + ni * 16 + r, kb));
#pragma unroll
      for (int mi = 0; mi < 4; ++mi)
#pragma unroll
        for (int ni = 0; ni < 4; ++ni)
          acc[mi][ni] = MFMA16(a4[mi], b4[ni], acc[mi][ni]);
    }
  }
#pragma unroll
  for (int mi = 0; mi < 4; ++mi)
#pragma unroll
    for (int ni = 0; ni < 4; ++ni)
#pragma unroll
      for (int i = 0; i < 4; ++i) {
        int m = m0 + wm * 64 + mi * 16 + 4 * g + i;
        int n = n0 + wn * 64 + ni * 16 + r;
        float v = acc[mi][ni][i] + b_out[n];
        __builtin_nontemporal_store(v, out + (size_t)m * 512 + n);
      }
}

extern "C" void kernel_launch(void* const* d_in, const int* in_sizes, int n_in,
                              void* d_out, int out_size, void* d_ws, size_t ws_size,
                              hipStream_t stream) {
  // Bind inputs BY SIZE (all six element counts distinct) — immune to order.
  const float *x = nullptr, *w_qkv = nullptr, *w_out = nullptr,
              *b_out = nullptr, *rpe = nullptr;
  const int* hop = nullptr;
  for (int i = 0; i < n_in; ++i) {
    switch (in_sizes[i]) {
      case 4194304: x     = (const float*)d_in[i]; break;  // (8,1024,512)
      case 786432:  w_qkv = (const float*)d_in[i]; break;  // (512,1536)
      case 262144:  w_out = (const float*)d_in[i]; break;  // (512,512)
      case 512:     b_out = (const float*)d_in[i]; break;  // (512,)
      case 72:      rpe   = (const float*)d_in[i]; break;  // (8,9)
      case 1048576: hop   = (const int*)d_in[i];   break;  // (1024,1024) int32
    }
  }

  float* out  = (float*)d_out;                 // f32 outputs
  float* attn = out + (size_t)4194304;         // attn section (8,8,1024,1024)

  char* ws = (char*)d_ws;
  unsigned short* q_    = (unsigned short*)(ws);                   // 8 MB
  unsigned short* k_    = (unsigned short*)(ws + (size_t) 8388608);// 8 MB
  unsigned short* valT  = (unsigned short*)(ws + (size_t)16777216);// 8 MB
  unsigned short* oh    = (unsigned short*)(ws + (size_t)25165824);// 8 MB
  unsigned short* wqT   = (unsigned short*)(ws + (size_t)33554432);// 1.5 MB
  unsigned short* woT   = (unsigned short*)(ws + (size_t)35127296);// 0.5 MB
  unsigned short* biasT = (unsigned short*)(ws + (size_t)35651584);// 16 MB
  // total ~51.6 MB of d_ws

  k_prep<<<dim3(4096), dim3(256), 0, stream>>>(w_qkv, w_out, wqT, woT);
  k_bias<<<dim3(4096), dim3(256), 0, stream>>>(hop, rpe, biasT);
  k_qkv<<<dim3(64, 12), dim3(256), 0, stream>>>(x, wqT, q_, k_, valT);
  k_attn<<<dim3(4096), dim3(256), 0, stream>>>(q_, k_, valT, biasT, attn, oh);
  k_out<<<dim3(64, 4), dim3(256), 0, stream>>>(oh, woT, b_out, out);
}

// Round 13
// 201.214 us; speedup vs baseline: 1.0217x; 1.0217x over previous
//
#include <hip/hip_runtime.h>

typedef __attribute__((ext_vector_type(8))) short bf16x8;
typedef __attribute__((ext_vector_type(4))) float f32x4;

#define MFMA16(A,B,C) __builtin_amdgcn_mfma_f32_16x16x32_bf16(A,B,C,0,0,0)

__device__ __forceinline__ unsigned short f2bf(float f){
  unsigned int u = __float_as_uint(f);
  u += 0x7FFFu + ((u >> 16) & 1u);        // round-to-nearest-even
  return (unsigned short)(u >> 16);
}
__device__ __forceinline__ float bf2f(unsigned short s){
  return __uint_as_float(((unsigned int)s) << 16);
}
// byte offset into a [rows][64] bf16 LDS tile (128B rows), XOR-swizzled (G4)
__device__ __forceinline__ int swz(int row, int kbyte){
  return (row * 128 + kbyte) ^ ((row & 7) << 4);
}

// ---------------- prep: transpose weights to n-major bf16 ------------------
__global__ __launch_bounds__(256) void k_prep(
    const float* __restrict__ w_qkv, const float* __restrict__ w_out,
    unsigned short* __restrict__ wqT, unsigned short* __restrict__ woT)
{
  int idx = blockIdx.x * 256 + threadIdx.x;
  if (idx < 1536 * 512) {
    int n = idx >> 9, kq = idx & 511;
    wqT[idx] = f2bf(w_qkv[(size_t)kq * 1536 + n]);
  } else {
    int j = idx - 1536 * 512;                  // < 262144
    int n = j >> 9, kq = j & 511;
    woT[j] = f2bf(w_out[(size_t)kq * 512 + n]);
  }
}

// ------ bias precompute: biasT[h][v][w] = rpe[h][hop[v][w]], w contiguous --
__global__ __launch_bounds__(256) void k_bias(
    const int* __restrict__ hop, const float* __restrict__ rpe_bias,
    unsigned short* __restrict__ biasT)
{
  __shared__ float rl[72];
  const int tid = threadIdx.x;
  if (tid < 72) rl[tid] = rpe_bias[tid];
  __syncthreads();
  const int idx = blockIdx.x * 256 + tid;      // (v,w) flat, coalesced
  const int hv = hop[idx];
#pragma unroll
  for (int h = 0; h < 8; ++h)
    biasT[((size_t)h << 20) + idx] = f2bf(rl[h * 9 + hv]);
}

// ---------------- QKV GEMM: qkv = x @ w_qkv (MFMA, bf16 in / f32 acc) ------
__global__ __launch_bounds__(256) void k_qkv(
    const float* __restrict__ x, const unsigned short* __restrict__ wqT,
    unsigned short* __restrict__ q, unsigned short* __restrict__ k_,
    unsigned short* __restrict__ valT)
{
  __shared__ char lds[32768];
  char* At = lds; char* Bt = lds + 16384;
  const int tid = threadIdx.x;
  const int wid = tid >> 6, lane = tid & 63, g = lane >> 4, r = lane & 15;
  const int wm = wid >> 1, wn = wid & 1;
  const int m0 = blockIdx.x * 128, n0 = blockIdx.y * 128;

  f32x4 acc[4][4];
#pragma unroll
  for (int a = 0; a < 4; ++a)
#pragma unroll
    for (int b = 0; b < 4; ++b) acc[a][b] = (f32x4){0.f, 0.f, 0.f, 0.f};

  for (int kt = 0; kt < 8; ++kt) {
    const int k0 = kt * 64;
    __syncthreads();
#pragma unroll
    for (int it = 0; it < 8; ++it) {
      int c = tid + it * 256;            // 128 rows x 16 chunks(4 f32)
      int row = c >> 4, c4 = c & 15;
      float4 xv = *reinterpret_cast<const float4*>(x + (size_t)(m0 + row) * 512 + k0 + c4 * 4);
      uint2 hv;
      hv.x = (unsigned)f2bf(xv.x) | ((unsigned)f2bf(xv.y) << 16);
      hv.y = (unsigned)f2bf(xv.z) | ((unsigned)f2bf(xv.w) << 16);
      *reinterpret_cast<uint2*>(At + swz(row, c4 * 8)) = hv;
    }
#pragma unroll
    for (int it = 0; it < 4; ++it) {
      int c = tid + it * 256;            // 128 rows x 8 chunks(16B)
      int row = c >> 3, c8 = c & 7;
      *reinterpret_cast<uint4*>(Bt + swz(row, c8 * 16)) =
          *reinterpret_cast<const uint4*>(wqT + (size_t)(n0 + row) * 512 + k0 + c8 * 8);
    }
    __syncthreads();
#pragma unroll
    for (int kk = 0; kk < 2; ++kk) {
      bf16x8 af[4], bf[4];
      const int kb = (kk * 32 + 8 * g) * 2;
#pragma unroll
      for (int mi = 0; mi < 4; ++mi)
        af[mi] = *reinterpret_cast<const bf16x8*>(At + swz(wm * 64 + mi * 16 + r, kb));
#pragma unroll
      for (int ni = 0; ni < 4; ++ni)
        bf[ni] = *reinterpret_cast<const bf16x8*>(Bt + swz(wn * 64 + ni * 16 + r, kb));
#pragma unroll
      for (int mi = 0; mi < 4; ++mi)
#pragma unroll
        for (int ni = 0; ni < 4; ++ni)
          acc[mi][ni] = MFMA16(af[mi], bf[ni], acc[mi][ni]);
    }
  }
  const int s = n0 >> 9;  // 0=q 1=k 2=val
#pragma unroll
  for (int mi = 0; mi < 4; ++mi)
#pragma unroll
    for (int ni = 0; ni < 4; ++ni)
#pragma unroll
      for (int i = 0; i < 4; ++i) {
        int m = m0 + wm * 64 + mi * 16 + 4 * g + i;   // D row = 4g+i (m89)
        int n = n0 + wn * 64 + ni * 16 + r;           // D col = lane&15
        int b = m >> 10, v = m & 1023;
        int cc = n & 511, h = cc >> 6, d = cc & 63;
        int bh = b * 8 + h;
        unsigned short bfv = f2bf(acc[mi][ni][i]);
        if (s == 2)      valT[((size_t)bh * 64 + d) * 1024 + v] = bfv;
        else if (s == 0) q [((size_t)bh * 1024 + v) * 64 + d] = bfv;
        else             k_[((size_t)bh * 1024 + v) * 64 + d] = bfv;
      }
}

// ---------------- attention: regs-scores + shfl softmax + PV ---------------
// One block = (b,h, 16 q-rows). Wave w owns score cols [256w, 256w+256).
// Work order (h, vt, b) with b INNERMOST: the 8 sharers of each bias tile are
// consecutive -> bias L2/L3-resident. XCD swizzle: XCD j owns head h=j, whose
// full working set (bias 2MB + K/V 2MB + q 1MB) is ~L2-resident.
#define PSTR 1032
__global__ __launch_bounds__(256, 3) void k_attn(
    const unsigned short* __restrict__ q, const unsigned short* __restrict__ k_,
    const unsigned short* __restrict__ valT,
    const unsigned short* __restrict__ biasT,
    float* __restrict__ attn, unsigned short* __restrict__ oh)
{
  __shared__ unsigned short P[16 * PSTR];   // bf16, 33 KB
  __shared__ float red[2][4][16];
  const int tid = threadIdx.x;
  const int wid = tid >> 6, lane = tid & 63, g = lane >> 4, r = lane & 15;
  // bijective XCD swizzle (4096 % 8 == 0): XCD j gets work ids [512j, 512j+512)
  const int blk = ((blockIdx.x & 7) << 9) | (blockIdx.x >> 3);
  const int h  = blk >> 9;                  // outermost: one head per XCD
  const int vt = (blk >> 3) & 63;
  const int b  = blk & 7;                   // innermost: bias-tile sharers adjacent
  const int bh = b * 8 + h;
  const int v0 = vt * 16;

  // stage bias tile [16 rows][1024 w] bf16 into P (uint4 = 8 elems, coalesced)
  const unsigned short* bb = biasT + ((size_t)h << 20) + (size_t)v0 * 1024;
#pragma unroll
  for (int it = 0; it < 8; ++it) {
    int e = tid + it * 256;                  // 0..2047: row=e>>7, chunk=e&127
    int row = e >> 7, c8 = e & 127;
    *reinterpret_cast<uint4*>(&P[row * PSTR + c8 * 8]) =
        *reinterpret_cast<const uint4*>(bb + (size_t)row * 1024 + c8 * 8);
  }

  // Q fragments in registers (A-operand: row=r, k-slice 8g)
  const unsigned short* qp = q + ((size_t)bh * 1024 + v0) * 64;
  bf16x8 qf[2];
#pragma unroll
  for (int kk = 0; kk < 2; ++kk)
    qf[kk] = *reinterpret_cast<const bf16x8*>(qp + r * 64 + kk * 32 + 8 * g);
  __syncthreads();

  // QK: scores in registers; bias from LDS
  const unsigned short* kb = k_ + (size_t)bh * 65536;
  f32x4 s[16];
#pragma unroll
  for (int ct = 0; ct < 16; ++ct) {
    const int wcol = wid * 256 + ct * 16 + r;
    f32x4 acc = (f32x4){0.f, 0.f, 0.f, 0.f};
#pragma unroll
    for (int kk = 0; kk < 2; ++kk) {
      bf16x8 kf = *reinterpret_cast<const bf16x8*>(kb + (size_t)wcol * 64 + kk * 32 + 8 * g);
      acc = MFMA16(qf[kk], kf, acc);
    }
#pragma unroll
    for (int i = 0; i < 4; ++i)
      s[ct][i] = (acc[i] + bf2f(P[(4 * g + i) * PSTR + wcol])) * 0.125f;
  }

  // per-row max: local over ct, then shfl over the 16-lane r-group
  float mx[4] = {-1e30f, -1e30f, -1e30f, -1e30f};
#pragma unroll
  for (int ct = 0; ct < 16; ++ct)
#pragma unroll
    for (int i = 0; i < 4; ++i) mx[i] = fmaxf(mx[i], s[ct][i]);
#pragma unroll
  for (int o = 1; o <= 8; o <<= 1)
#pragma unroll
    for (int i = 0; i < 4; ++i) mx[i] = fmaxf(mx[i], __shfl_xor(mx[i], o, 64));
  if (r == 0)
#pragma unroll
    for (int i = 0; i < 4; ++i) red[0][wid][4 * g + i] = mx[i];
  __syncthreads();
#pragma unroll
  for (int i = 0; i < 4; ++i) {
    float M = red[0][0][4 * g + i];
#pragma unroll
    for (int w = 1; w < 4; ++w) M = fmaxf(M, red[0][w][4 * g + i]);
    mx[i] = M;
  }

  // exp + per-row sum
  float sm[4] = {0.f, 0.f, 0.f, 0.f};
#pragma unroll
  for (int ct = 0; ct < 16; ++ct)
#pragma unroll
    for (int i = 0; i < 4; ++i) {
      float e = __expf(s[ct][i] - mx[i]);
      s[ct][i] = e;
      sm[i] += e;
    }
#pragma unroll
  for (int o = 1; o <= 8; o <<= 1)
#pragma unroll
    for (int i = 0; i < 4; ++i) sm[i] += __shfl_xor(sm[i], o, 64);
  if (r == 0)
#pragma unroll
    for (int i = 0; i < 4; ++i) red[1][wid][4 * g + i] = sm[i];
  __syncthreads();                 // all QK bias reads done before P overwrite
  float inv[4];
#pragma unroll
  for (int i = 0; i < 4; ++i) {
    float T = red[1][0][4 * g + i] + red[1][1][4 * g + i] +
              red[1][2][4 * g + i] + red[1][3][4 * g + i];
    inv[i] = 1.0f / T;
  }

  // normalize into bf16 P only (no scattered global writes)
#pragma unroll
  for (int ct = 0; ct < 16; ++ct) {
    const int col = wid * 256 + ct * 16 + r;
#pragma unroll
    for (int i = 0; i < 4; ++i)
      P[(4 * g + i) * PSTR + col] = f2bf(s[ct][i] * inv[i]);
  }
  __syncthreads();

  // coalesced attn write from P: lane -> f32x4 (16B), 1KB contiguous per wave.
  float* ab = attn + ((size_t)bh * 1024 + v0) * 1024;
#pragma unroll
  for (int it = 0; it < 16; ++it) {
    int e = tid + it * 256;                 // 0..4095: row=e>>8, quad=e&255
    int row = e >> 8, q4 = e & 255;
    uint2 pv = *reinterpret_cast<const uint2*>(&P[row * PSTR + q4 * 4]);
    f32x4 o;
    o[0] = bf2f((unsigned short)(pv.x      ));
    o[1] = bf2f((unsigned short)(pv.x >> 16));
    o[2] = bf2f((unsigned short)(pv.y      ));
    o[3] = bf2f((unsigned short)(pv.y >> 16));
    __builtin_nontemporal_store(o, reinterpret_cast<f32x4*>(ab + (size_t)row * 1024 + q4 * 4));
  }

  // PV: out(16x64) = P(16x1024) @ val(1024x64); wave owns 16 out cols.
  const unsigned short* vT = valT + ((size_t)bh * 64 + wid * 16) * 1024;
  f32x4 a0 = (f32x4){0.f,0.f,0.f,0.f}, a1 = a0;
  for (int kc = 0; kc < 32; kc += 2) {
    const int base = r * PSTR, vbase = kc * 32 + 8 * g;
    bf16x8 p0 = *reinterpret_cast<const bf16x8*>(&P[base + vbase]);
    bf16x8 p1 = *reinterpret_cast<const bf16x8*>(&P[base + vbase + 32]);
    bf16x8 v0_ = *reinterpret_cast<const bf16x8*>(vT + (size_t)r * 1024 + vbase);
    bf16x8 v1_ = *reinterpret_cast<const bf16x8*>(vT + (size_t)r * 1024 + vbase + 32);
    a0 = MFMA16(p0, v0_, a0);
    a1 = MFMA16(p1, v1_, a1);
  }
  f32x4 acc = a0 + a1;
#pragma unroll
  for (int i = 0; i < 4; ++i) {
    size_t oi = ((size_t)(b * 1024 + v0 + 4 * g + i)) * 512 + h * 64 + wid * 16 + r;
    oh[oi] = f2bf(acc[i]);
  }
}

// ---------------- output GEMM: out = oh @ w_out + b_out (f32 out) ----------
__global__ __launch_bounds__(256) void k_out(
    const unsigned short* __restrict__ oh, const unsigned short* __restrict__ woT,
    const float* __restrict__ b_out, float* __restrict__ out)
{
  __shared__ char lds[32768];
  char* At = lds; char* Bt = lds + 16384;
  const int tid = threadIdx.x;
  const int wid = tid >> 6, lane = tid & 63, g = lane >> 4, r = lane & 15;
  const int wm = wid >> 1, wn = wid & 1;
  const int m0 = blockIdx.x * 128, n0 = blockIdx.y * 128;

  f32x4 acc[4][4];
#pragma unroll
  for (int a = 0; a < 4; ++a)
#pragma unroll
    for (int b = 0; b < 4; ++b) acc[a][b] = (f32x4){0.f, 0.f, 0.f, 0.f};

  for (int kt = 0; kt < 8; ++kt) {
    const int k0 = kt * 64;
    __syncthreads();
#pragma unroll
    for (int it = 0; it < 4; ++it) {
      int c = tid + it * 256;
      int row = c >> 3, c8 = c & 7;
      *reinterpret_cast<uint4*>(At + swz(row, c8 * 16)) =
          *reinterpret_cast<const uint4*>(oh + (size_t)(m0 + row) * 512 + k0 + c8 * 8);
      *reinterpret_cast<uint4*>(Bt + swz(row, c8 * 16)) =
          *reinterpret_cast<const uint4*>(woT + (size_t)(n0 + row) * 512 + k0 + c8 * 8);
    }
    __syncthreads();
#pragma unroll
    for (int kk = 0; kk < 2; ++kk) {
      bf16x8 a4[4], b4[4];
      const int kb = (kk * 32 + 8 * g) * 2;
#pragma unroll
      for (int mi = 0; mi < 4; ++mi)
        a4[mi] = *reinterpret_cast<const bf16x8*>(At + swz(wm * 64 + mi * 16 + r, kb));
#pragma unroll
      for (int ni = 0; ni < 4; ++ni)
        b4[ni] = *reinterpret_cast<const bf16x8*>(Bt + swz(wn * 64 + ni * 16 + r, kb));
#pragma unroll
      for (int mi = 0; mi < 4; ++mi)
#pragma unroll
        for (int ni = 0; ni < 4; ++ni)
          acc[mi][ni] = MFMA16(a4[mi], b4[ni], acc[mi][ni]);
    }
  }
#pragma unroll
  for (int mi = 0; mi < 4; ++mi)
#pragma unroll
    for (int ni = 0; ni < 4; ++ni)
#pragma unroll
      for (int i = 0; i < 4; ++i) {
        int m = m0 + wm * 64 + mi * 16 + 4 * g + i;
        int n = n0 + wn * 64 + ni * 16 + r;
        float v = acc[mi][ni][i] + b_out[n];
        __builtin_nontemporal_store(v, out + (size_t)m * 512 + n);
      }
}

extern "C" void kernel_launch(void* const* d_in, const int* in_sizes, int n_in,
                              void* d_out, int out_size, void* d_ws, size_t ws_size,
                              hipStream_t stream) {
  // Bind inputs BY SIZE (all six element counts distinct) — immune to order.
  const float *x = nullptr, *w_qkv = nullptr, *w_out = nullptr,
              *b_out = nullptr, *rpe = nullptr;
  const int* hop = nullptr;
  for (int i = 0; i < n_in; ++i) {
    switch (in_sizes[i]) {
      case 4194304: x     = (const float*)d_in[i]; break;  // (8,1024,512)
      case 786432:  w_qkv = (const float*)d_in[i]; break;  // (512,1536)
      case 262144:  w_out = (const float*)d_in[i]; break;  // (512,512)
      case 512:     b_out = (const float*)d_in[i]; break;  // (512,)
      case 72:      rpe   = (const float*)d_in[i]; break;  // (8,9)
      case 1048576: hop   = (const int*)d_in[i];   break;  // (1024,1024) int32
    }
  }

  float* out  = (float*)d_out;                 // f32 outputs
  float* attn = out + (size_t)4194304;         // attn section (8,8,1024,1024)

  char* ws = (char*)d_ws;
  unsigned short* q_    = (unsigned short*)(ws);                   // 8 MB
  unsigned short* k_    = (unsigned short*)(ws + (size_t) 8388608);// 8 MB
  unsigned short* valT  = (unsigned short*)(ws + (size_t)16777216);// 8 MB
  unsigned short* oh    = (unsigned short*)(ws + (size_t)25165824);// 8 MB
  unsigned short* wqT   = (unsigned short*)(ws + (size_t)33554432);// 1.5 MB
  unsigned short* woT   = (unsigned short*)(ws + (size_t)35127296);// 0.5 MB
  unsigned short* biasT = (unsigned short*)(ws + (size_t)35651584);// 16 MB
  // total ~51.6 MB of d_ws

  k_prep<<<dim3(4096), dim3(256), 0, stream>>>(w_qkv, w_out, wqT, woT);
  k_bias<<<dim3(4096), dim3(256), 0, stream>>>(hop, rpe, biasT);
  k_qkv<<<dim3(64, 12), dim3(256), 0, stream>>>(x, wqT, q_, k_, valT);
  k_attn<<<dim3(4096), dim3(256), 0, stream>>>(q_, k_, valT, biasT, attn, oh);
  k_out<<<dim3(64, 4), dim3(256), 0, stream>>>(oh, woT, b_out, out);
}

// Round 14
// 200.108 us; speedup vs baseline: 1.0274x; 1.0055x over previous
//
#include <hip/hip_runtime.h>

typedef __attribute__((ext_vector_type(8))) short bf16x8;
typedef __attribute__((ext_vector_type(4))) float f32x4;

#define MFMA16(A,B,C) __builtin_amdgcn_mfma_f32_16x16x32_bf16(A,B,C,0,0,0)

__device__ __forceinline__ unsigned short f2bf(float f){
  unsigned int u = __float_as_uint(f);
  u += 0x7FFFu + ((u >> 16) & 1u);        // round-to-nearest-even
  return (unsigned short)(u >> 16);
}
__device__ __forceinline__ float bf2f(unsigned short s){
  return __uint_as_float(((unsigned int)s) << 16);
}
// byte offset into a [rows][64] bf16 LDS tile (128B rows), XOR-swizzled (G4)
__device__ __forceinline__ int swz(int row, int kbyte){
  return (row * 128 + kbyte) ^ ((row & 7) << 4);
}

// ---- prep: transpose weights to n-major bf16 + pre-convert x to bf16 ------
__global__ __launch_bounds__(256) void k_prep(
    const float* __restrict__ w_qkv, const float* __restrict__ w_out,
    const float* __restrict__ x,
    unsigned short* __restrict__ wqT, unsigned short* __restrict__ woT,
    unsigned short* __restrict__ xb)
{
  int idx = blockIdx.x * 256 + threadIdx.x;
  if (idx < 1536 * 512) {
    int n = idx >> 9, kq = idx & 511;
    wqT[idx] = f2bf(w_qkv[(size_t)kq * 1536 + n]);
  } else if (idx < 1536 * 512 + 262144) {
    int j = idx - 1536 * 512;                  // < 262144
    int n = j >> 9, kq = j & 511;
    woT[j] = f2bf(w_out[(size_t)kq * 512 + n]);
  } else {
    int j = idx - (1536 * 512 + 262144);       // < 1048576, 4 f32 each
    float4 xv = *reinterpret_cast<const float4*>(x + (size_t)j * 4);
    ushort4 o;
    o.x = f2bf(xv.x); o.y = f2bf(xv.y); o.z = f2bf(xv.z); o.w = f2bf(xv.w);
    *reinterpret_cast<ushort4*>(xb + (size_t)j * 4) = o;
  }
}

// ------ bias precompute: biasT[h][v][w] = rpe[h][hop[v][w]], w contiguous --
__global__ __launch_bounds__(256) void k_bias(
    const int* __restrict__ hop, const float* __restrict__ rpe_bias,
    unsigned short* __restrict__ biasT)
{
  __shared__ float rl[72];
  const int tid = threadIdx.x;
  if (tid < 72) rl[tid] = rpe_bias[tid];
  __syncthreads();
  const int idx = blockIdx.x * 256 + tid;      // (v,w) flat, coalesced
  const int hv = hop[idx];
#pragma unroll
  for (int h = 0; h < 8; ++h)
    biasT[((size_t)h << 20) + idx] = f2bf(rl[h * 9 + hv]);
}

// ---------------- QKV GEMM: qkv = xb @ w_qkv (MFMA, bf16 in / f32 acc) -----
__global__ __launch_bounds__(256) void k_qkv(
    const unsigned short* __restrict__ xb, const unsigned short* __restrict__ wqT,
    unsigned short* __restrict__ q, unsigned short* __restrict__ k_,
    unsigned short* __restrict__ valT)
{
  __shared__ char lds[32768];
  char* At = lds; char* Bt = lds + 16384;
  const int tid = threadIdx.x;
  const int wid = tid >> 6, lane = tid & 63, g = lane >> 4, r = lane & 15;
  const int wm = wid >> 1, wn = wid & 1;
  const int m0 = blockIdx.x * 128, n0 = blockIdx.y * 128;

  f32x4 acc[4][4];
#pragma unroll
  for (int a = 0; a < 4; ++a)
#pragma unroll
    for (int b = 0; b < 4; ++b) acc[a][b] = (f32x4){0.f, 0.f, 0.f, 0.f};

  for (int kt = 0; kt < 8; ++kt) {
    const int k0 = kt * 64;
    __syncthreads();
#pragma unroll
    for (int it = 0; it < 4; ++it) {
      int c = tid + it * 256;            // 128 rows x 8 chunks(16B)
      int row = c >> 3, c8 = c & 7;
      *reinterpret_cast<uint4*>(At + swz(row, c8 * 16)) =
          *reinterpret_cast<const uint4*>(xb + (size_t)(m0 + row) * 512 + k0 + c8 * 8);
      *reinterpret_cast<uint4*>(Bt + swz(row, c8 * 16)) =
          *reinterpret_cast<const uint4*>(wqT + (size_t)(n0 + row) * 512 + k0 + c8 * 8);
    }
    __syncthreads();
#pragma unroll
    for (int kk = 0; kk < 2; ++kk) {
      bf16x8 af[4], bf[4];
      const int kb = (kk * 32 + 8 * g) * 2;
#pragma unroll
      for (int mi = 0; mi < 4; ++mi)
        af[mi] = *reinterpret_cast<const bf16x8*>(At + swz(wm * 64 + mi * 16 + r, kb));
#pragma unroll
      for (int ni = 0; ni < 4; ++ni)
        bf[ni] = *reinterpret_cast<const bf16x8*>(Bt + swz(wn * 64 + ni * 16 + r, kb));
#pragma unroll
      for (int mi = 0; mi < 4; ++mi)
#pragma unroll
        for (int ni = 0; ni < 4; ++ni)
          acc[mi][ni] = MFMA16(af[mi], bf[ni], acc[mi][ni]);
    }
  }
  const int s = n0 >> 9;  // 0=q 1=k 2=val
#pragma unroll
  for (int mi = 0; mi < 4; ++mi)
#pragma unroll
    for (int ni = 0; ni < 4; ++ni)
#pragma unroll
      for (int i = 0; i < 4; ++i) {
        int m = m0 + wm * 64 + mi * 16 + 4 * g + i;   // D row = 4g+i (m89)
        int n = n0 + wn * 64 + ni * 16 + r;           // D col = lane&15
        int b = m >> 10, v = m & 1023;
        int cc = n & 511, h = cc >> 6, d = cc & 63;
        int bh = b * 8 + h;
        unsigned short bfv = f2bf(acc[mi][ni][i]);
        if (s == 2)      valT[((size_t)bh * 64 + d) * 1024 + v] = bfv;
        else if (s == 0) q [((size_t)bh * 1024 + v) * 64 + d] = bfv;
        else             k_[((size_t)bh * 1024 + v) * 64 + d] = bfv;
      }
}

// ---------------- attention: regs-scores + shfl softmax + PV ---------------
// One block = (b,h, 16 q-rows). Wave w owns score cols [256w, 256w+256).
// Work order (h, vt, b) with b INNERMOST; XCD j owns head h=j.
#define PSTR 1032
__global__ __launch_bounds__(256, 4) void k_attn(
    const unsigned short* __restrict__ q, const unsigned short* __restrict__ k_,
    const unsigned short* __restrict__ valT,
    const unsigned short* __restrict__ biasT,
    float* __restrict__ attn, unsigned short* __restrict__ oh)
{
  __shared__ unsigned short P[16 * PSTR];   // bf16, 33 KB
  __shared__ float red[2][4][16];
  const int tid = threadIdx.x;
  const int wid = tid >> 6, lane = tid & 63, g = lane >> 4, r = lane & 15;
  // bijective XCD swizzle (4096 % 8 == 0): XCD j gets work ids [512j, 512j+512)
  const int blk = ((blockIdx.x & 7) << 9) | (blockIdx.x >> 3);
  const int h  = blk >> 9;                  // outermost: one head per XCD
  const int vt = (blk >> 3) & 63;
  const int b  = blk & 7;                   // innermost: bias-tile sharers adjacent
  const int bh = b * 8 + h;
  const int v0 = vt * 16;

  // stage bias tile [16 rows][1024 w] bf16 into P (uint4 = 8 elems, coalesced)
  const unsigned short* bb = biasT + ((size_t)h << 20) + (size_t)v0 * 1024;
#pragma unroll
  for (int it = 0; it < 8; ++it) {
    int e = tid + it * 256;                  // 0..2047: row=e>>7, chunk=e&127
    int row = e >> 7, c8 = e & 127;
    *reinterpret_cast<uint4*>(&P[row * PSTR + c8 * 8]) =
        *reinterpret_cast<const uint4*>(bb + (size_t)row * 1024 + c8 * 8);
  }

  // Q fragments in registers (A-operand: row=r, k-slice 8g)
  const unsigned short* qp = q + ((size_t)bh * 1024 + v0) * 64;
  bf16x8 qf[2];
#pragma unroll
  for (int kk = 0; kk < 2; ++kk)
    qf[kk] = *reinterpret_cast<const bf16x8*>(qp + r * 64 + kk * 32 + 8 * g);
  __syncthreads();

  // QK: scores in registers; bias from LDS
  const unsigned short* kb = k_ + (size_t)bh * 65536;
  f32x4 s[16];
#pragma unroll
  for (int ct = 0; ct < 16; ++ct) {
    const int wcol = wid * 256 + ct * 16 + r;
    f32x4 acc = (f32x4){0.f, 0.f, 0.f, 0.f};
#pragma unroll
    for (int kk = 0; kk < 2; ++kk) {
      bf16x8 kf = *reinterpret_cast<const bf16x8*>(kb + (size_t)wcol * 64 + kk * 32 + 8 * g);
      acc = MFMA16(qf[kk], kf, acc);
    }
#pragma unroll
    for (int i = 0; i < 4; ++i)
      s[ct][i] = (acc[i] + bf2f(P[(4 * g + i) * PSTR + wcol])) * 0.125f;
  }

  // per-row max: local over ct, then shfl over the 16-lane r-group
  float mx[4] = {-1e30f, -1e30f, -1e30f, -1e30f};
#pragma unroll
  for (int ct = 0; ct < 16; ++ct)
#pragma unroll
    for (int i = 0; i < 4; ++i) mx[i] = fmaxf(mx[i], s[ct][i]);
#pragma unroll
  for (int o = 1; o <= 8; o <<= 1)
#pragma unroll
    for (int i = 0; i < 4; ++i) mx[i] = fmaxf(mx[i], __shfl_xor(mx[i], o, 64));
  if (r == 0)
#pragma unroll
    for (int i = 0; i < 4; ++i) red[0][wid][4 * g + i] = mx[i];
  __syncthreads();
#pragma unroll
  for (int i = 0; i < 4; ++i) {
    float M = red[0][0][4 * g + i];
#pragma unroll
    for (int w = 1; w < 4; ++w) M = fmaxf(M, red[0][w][4 * g + i]);
    mx[i] = M;
  }

  // exp + per-row sum
  float sm[4] = {0.f, 0.f, 0.f, 0.f};
#pragma unroll
  for (int ct = 0; ct < 16; ++ct)
#pragma unroll
    for (int i = 0; i < 4; ++i) {
      float e = __expf(s[ct][i] - mx[i]);
      s[ct][i] = e;
      sm[i] += e;
    }
#pragma unroll
  for (int o = 1; o <= 8; o <<= 1)
#pragma unroll
    for (int i = 0; i < 4; ++i) sm[i] += __shfl_xor(sm[i], o, 64);
  if (r == 0)
#pragma unroll
    for (int i = 0; i < 4; ++i) red[1][wid][4 * g + i] = sm[i];
  __syncthreads();                 // all QK bias reads done before P overwrite
  float inv[4];
#pragma unroll
  for (int i = 0; i < 4; ++i) {
    float T = red[1][0][4 * g + i] + red[1][1][4 * g + i] +
              red[1][2][4 * g + i] + red[1][3][4 * g + i];
    inv[i] = 1.0f / T;
  }

  // normalize into bf16 P only (no scattered global writes)
#pragma unroll
  for (int ct = 0; ct < 16; ++ct) {
    const int col = wid * 256 + ct * 16 + r;
#pragma unroll
    for (int i = 0; i < 4; ++i)
      P[(4 * g + i) * PSTR + col] = f2bf(s[ct][i] * inv[i]);
  }
  __syncthreads();

  // coalesced attn write from P: lane -> f32x4 (16B), 1KB contiguous per wave.
  float* ab = attn + ((size_t)bh * 1024 + v0) * 1024;
#pragma unroll
  for (int it = 0; it < 16; ++it) {
    int e = tid + it * 256;                 // 0..4095: row=e>>8, quad=e&255
    int row = e >> 8, q4 = e & 255;
    uint2 pv = *reinterpret_cast<const uint2*>(&P[row * PSTR + q4 * 4]);
    f32x4 o;
    o[0] = bf2f((unsigned short)(pv.x      ));
    o[1] = bf2f((unsigned short)(pv.x >> 16));
    o[2] = bf2f((unsigned short)(pv.y      ));
    o[3] = bf2f((unsigned short)(pv.y >> 16));
    __builtin_nontemporal_store(o, reinterpret_cast<f32x4*>(ab + (size_t)row * 1024 + q4 * 4));
  }

  // PV: out(16x64) = P(16x1024) @ val(1024x64); wave owns 16 out cols.
  const unsigned short* vT = valT + ((size_t)bh * 64 + wid * 16) * 1024;
  f32x4 a0 = (f32x4){0.f,0.f,0.f,0.f}, a1 = a0;
  for (int kc = 0; kc < 32; kc += 2) {
    const int base = r * PSTR, vbase = kc * 32 + 8 * g;
    bf16x8 p0 = *reinterpret_cast<const bf16x8*>(&P[base + vbase]);
    bf16x8 p1 = *reinterpret_cast<const bf16x8*>(&P[base + vbase + 32]);
    bf16x8 v0_ = *reinterpret_cast<const bf16x8*>(vT + (size_t)r * 1024 + vbase);
    bf16x8 v1_ = *reinterpret_cast<const bf16x8*>(vT + (size_t)r * 1024 + vbase + 32);
    a0 = MFMA16(p0, v0_, a0);
    a1 = MFMA16(p1, v1_, a1);
  }
  f32x4 acc = a0 + a1;
#pragma unroll
  for (int i = 0; i < 4; ++i) {
    size_t oi = ((size_t)(b * 1024 + v0 + 4 * g + i)) * 512 + h * 64 + wid * 16 + r;
    oh[oi] = f2bf(acc[i]);
  }
}

// ---------------- output GEMM: out = oh @ w_out + b_out (f32 out) ----------
__global__ __launch_bounds__(256) void k_out(
    const unsigned short* __restrict__ oh, const unsigned short* __restrict__ woT,
    const float* __restrict__ b_out, float* __restrict__ out)
{
  __shared__ char lds[32768];
  char* At = lds; char* Bt = lds + 16384;
  const int tid = threadIdx.x;
  const int wid = tid >> 6, lane = tid & 63, g = lane >> 4, r = lane & 15;
  const int wm = wid >> 1, wn = wid & 1;
  const int m0 = blockIdx.x * 128, n0 = blockIdx.y * 128;

  f32x4 acc[4][4];
#pragma unroll
  for (int a = 0; a < 4; ++a)
#pragma unroll
    for (int b = 0; b < 4; ++b) acc[a][b] = (f32x4){0.f, 0.f, 0.f, 0.f};

  for (int kt = 0; kt < 8; ++kt) {
    const int k0 = kt * 64;
    __syncthreads();
#pragma unroll
    for (int it = 0; it < 4; ++it) {
      int c = tid + it * 256;
      int row = c >> 3, c8 = c & 7;
      *reinterpret_cast<uint4*>(At + swz(row, c8 * 16)) =
          *reinterpret_cast<const uint4*>(oh + (size_t)(m0 + row) * 512 + k0 + c8 * 8);
      *reinterpret_cast<uint4*>(Bt + swz(row, c8 * 16)) =
          *reinterpret_cast<const uint4*>(woT + (size_t)(n0 + row) * 512 + k0 + c8 * 8);
    }
    __syncthreads();
#pragma unroll
    for (int kk = 0; kk < 2; ++kk) {
      bf16x8 a4[4], b4[4];
      const int kb = (kk * 32 + 8 * g) * 2;
#pragma unroll
      for (int mi = 0; mi < 4; ++mi)
        a4[mi] = *reinterpret_cast<const bf16x8*>(At + swz(wm * 64 + mi * 16 + r, kb));
#pragma unroll
      for (int ni = 0; ni < 4; ++ni)
        b4[ni] = *reinterpret_cast<const bf16x8*>(Bt + swz(wn * 64 + ni * 16 + r, kb));
#pragma unroll
      for (int mi = 0; mi < 4; ++mi)
#pragma unroll
        for (int ni = 0; ni < 4; ++ni)
          acc[mi][ni] = MFMA16(a4[mi], b4[ni], acc[mi][ni]);
    }
  }
#pragma unroll
  for (int mi = 0; mi < 4; ++mi)
#pragma unroll
    for (int ni = 0; ni < 4; ++ni)
#pragma unroll
      for (int i = 0; i < 4; ++i) {
        int m = m0 + wm * 64 + mi * 16 + 4 * g + i;
        int n = n0 + wn * 64 + ni * 16 + r;
        float v = acc[mi][ni][i] + b_out[n];
        __builtin_nontemporal_store(v, out + (size_t)m * 512 + n);
      }
}

extern "C" void kernel_launch(void* const* d_in, const int* in_sizes, int n_in,
                              void* d_out, int out_size, void* d_ws, size_t ws_size,
                              hipStream_t stream) {
  // Bind inputs BY SIZE (all six element counts distinct) — immune to order.
  const float *x = nullptr, *w_qkv = nullptr, *w_out = nullptr,
              *b_out = nullptr, *rpe = nullptr;
  const int* hop = nullptr;
  for (int i = 0; i < n_in; ++i) {
    switch (in_sizes[i]) {
      case 4194304: x     = (const float*)d_in[i]; break;  // (8,1024,512)
      case 786432:  w_qkv = (const float*)d_in[i]; break;  // (512,1536)
      case 262144:  w_out = (const float*)d_in[i]; break;  // (512,512)
      case 512:     b_out = (const float*)d_in[i]; break;  // (512,)
      case 72:      rpe   = (const float*)d_in[i]; break;  // (8,9)
      case 1048576: hop   = (const int*)d_in[i];   break;  // (1024,1024) int32
    }
  }

  float* out  = (float*)d_out;                 // f32 outputs
  float* attn = out + (size_t)4194304;         // attn section (8,8,1024,1024)

  char* ws = (char*)d_ws;
  unsigned short* q_    = (unsigned short*)(ws);                   // 8 MB
  unsigned short* k_    = (unsigned short*)(ws + (size_t) 8388608);// 8 MB
  unsigned short* valT  = (unsigned short*)(ws + (size_t)16777216);// 8 MB
  unsigned short* oh    = (unsigned short*)(ws + (size_t)25165824);// 8 MB
  unsigned short* wqT   = (unsigned short*)(ws + (size_t)33554432);// 1.5 MB
  unsigned short* woT   = (unsigned short*)(ws + (size_t)35127296);// 0.5 MB
  unsigned short* biasT = (unsigned short*)(ws + (size_t)35651584);// 16 MB
  unsigned short* xb    = (unsigned short*)(ws + (size_t)52428800);// 8 MB
  // total ~60 MB of d_ws (>=64 MB proven in round 3)

  // prep grid: 1536*512 wqT + 262144 woT + 1048576 xb-quads = 2097152 threads
  k_prep<<<dim3(8192), dim3(256), 0, stream>>>(w_qkv, w_out, x, wqT, woT, xb);
  k_bias<<<dim3(4096), dim3(256), 0, stream>>>(hop, rpe, biasT);
  k_qkv<<<dim3(64, 12), dim3(256), 0, stream>>>(xb, wqT, q_, k_, valT);
  k_attn<<<dim3(4096), dim3(256), 0, stream>>>(q_, k_, valT, biasT, attn, oh);
  k_out<<<dim3(64, 4), dim3(256), 0, stream>>>(oh, woT, b_out, out);
}